// Round 2
// baseline (737.772 us; speedup 1.0000x reference)
//
#include <hip/hip_runtime.h>

typedef unsigned short u16;
typedef unsigned int   u32;
typedef __bf16 bf16x8 __attribute__((ext_vector_type(8)));
typedef float  f32x4  __attribute__((ext_vector_type(4)));
typedef float  f32x2  __attribute__((ext_vector_type(2)));
typedef unsigned short u16x8 __attribute__((ext_vector_type(8)));

__device__ __forceinline__ u16 f2bf(float f){
  union { float f; u32 i; } v; v.f = f;
  u32 u = v.i;
  u += 0x7fffu + ((u >> 16) & 1u);   // RNE (finite values only)
  return (u16)(u >> 16);
}
__device__ __forceinline__ float tanh_fast(float x){
  x = fminf(fmaxf(x, -12.f), 12.f);
  float t = __builtin_amdgcn_exp2f(x * 2.885390081777926815f); // e^{2x}
  return (t - 1.f) * __builtin_amdgcn_rcpf(t + 1.f);
}

// ------- transpose+downcast: in f32[R][C] -> out bf16[C][R]; R,C mult of 64
__global__ __launch_bounds__(256) void transpose_cast_k(
    const float* __restrict__ in, u16* __restrict__ out, int R, int C)
{
  __shared__ u16 tile[64][65];
  const int tx = threadIdx.x & 63;
  const int ty = threadIdx.x >> 6;        // 0..3
  const int c0 = blockIdx.x * 64;
  const int r0 = blockIdx.y * 64;
#pragma unroll
  for (int rr = 0; rr < 16; ++rr){
    int r = ty + rr * 4;
    tile[r][tx] = f2bf(in[(size_t)(r0 + r) * C + c0 + tx]);
  }
  __syncthreads();
#pragma unroll
  for (int rr = 0; rr < 16; ++rr){
    int r = ty + rr * 4;                  // input-col index within tile
    out[(size_t)(c0 + r) * R + r0 + tx] = tile[tx][r];
  }
}

// ---------------- fused PILayer kernel, 64 pairs per block ----------------
// inter = bf16(p1[i]+p1[j])      -> LDS  [64][72]  bf16
// h     = bf16(tanh(inter @ W1)) -> LDS  [64][264] bf16  (256 used, padded)
// h2    = h @ W2 (fp32 acc, D[n][m] orientation)
// out[m][c] = sum_b h2[m][c*8+b] * basis[m][b]   (fp32)
__global__ __launch_bounds__(256, 2) void pilayer_kernel(
    const float* __restrict__ p1,     // [N_NODES][64] f32
    const int* __restrict__ pair_i,   // [NP]
    const int* __restrict__ pair_j,   // [NP]
    const float* __restrict__ basis,  // [NP][8] f32
    const u16* __restrict__ w1t,      // [256][64] bf16 (W1 transposed)
    const u16* __restrict__ w2t,      // [512][256] bf16 (W2 transposed)
    float* __restrict__ out,          // [NP][64] f32
    int n_pairs)
{
  __shared__ __align__(16) u16 sh_h[64 * 264];
  __shared__ __align__(16) u16 sh_inter[64 * 72];

  const int tid  = threadIdx.x;
  const int blk  = blockIdx.x;
  const int lane = tid & 63;
  const int wave = tid >> 6;     // 0..3
  const int m16  = lane & 15;
  const int q    = lane >> 4;    // quad 0..3

  // ---- Phase 0: gather inter = bf16(p1[i] + p1[j]) into LDS ----
  {
    int m   = tid >> 2;          // pair row 0..63
    int seg = tid & 3;           // 16 floats per segment
    int p   = blk * 64 + m;
    if (p >= n_pairs) p = n_pairs - 1;
    const f32x4* pi = (const f32x4*)(p1 + (size_t)pair_i[p] * 64 + seg * 16);
    const f32x4* pj = (const f32x4*)(p1 + (size_t)pair_j[p] * 64 + seg * 16);
    f32x4 a0 = pi[0], a1 = pi[1], a2 = pi[2], a3 = pi[3];
    f32x4 b0 = pj[0], b1 = pj[1], b2 = pj[2], b3 = pj[3];
    u16x8 r0, r1;
#pragma unroll
    for (int e = 0; e < 4; ++e){
      r0[e]     = f2bf(a0[e] + b0[e]);
      r0[e + 4] = f2bf(a1[e] + b1[e]);
      r1[e]     = f2bf(a2[e] + b2[e]);
      r1[e + 4] = f2bf(a3[e] + b3[e]);
    }
    u16x8* dst = (u16x8*)(sh_inter + m * 72 + seg * 16);
    dst[0] = r0; dst[1] = r1;
  }
  __syncthreads();

  // ---- Phase 1: h = tanh(inter @ W1) -> sh_h ----
  // A = W1t rows (n256 dim), B = inter rows (pair dim). D[n][m]:
  // col(lane&15)=pair, row(q*4+reg)=n  -> 4 consecutive n per lane.
  {
    bf16x8 bfr[4][2];
#pragma unroll
    for (int mt = 0; mt < 4; ++mt)
#pragma unroll
      for (int kk = 0; kk < 2; ++kk)
        bfr[mt][kk] = *(const bf16x8*)(sh_inter + (mt*16 + m16)*72 + kk*32 + q*8);
#pragma unroll
    for (int nt = 0; nt < 4; ++nt){
      const int n0 = wave*64 + nt*16;
      const bf16x8 af0 = *(const bf16x8*)(w1t + (size_t)(n0 + m16)*64 +      q*8);
      const bf16x8 af1 = *(const bf16x8*)(w1t + (size_t)(n0 + m16)*64 + 32 + q*8);
#pragma unroll
      for (int mt = 0; mt < 4; ++mt){
        f32x4 acc = {0.f, 0.f, 0.f, 0.f};
        acc = __builtin_amdgcn_mfma_f32_16x16x32_bf16(af0, bfr[mt][0], acc, 0, 0, 0);
        acc = __builtin_amdgcn_mfma_f32_16x16x32_bf16(af1, bfr[mt][1], acc, 0, 0, 0);
        u32 lo = (u32)f2bf(tanh_fast(acc[0])) | ((u32)f2bf(tanh_fast(acc[1])) << 16);
        u32 hi = (u32)f2bf(tanh_fast(acc[2])) | ((u32)f2bf(tanh_fast(acc[3])) << 16);
        u32* dst = (u32*)(sh_h + (size_t)(mt*16 + m16)*264 + n0 + q*4);
        dst[0] = lo; dst[1] = hi;    // ds_write_b64
      }
    }
  }
  __syncthreads();

  // ---- Phase 2: h2 = h @ W2 (D[n][m]), fold basis, store out ----
  {
    f32x4 acc[8][4];
#pragma unroll
    for (int nt = 0; nt < 8; ++nt)
#pragma unroll
      for (int mt = 0; mt < 4; ++mt)
        acc[nt][mt] = (f32x4){0.f, 0.f, 0.f, 0.f};

    const u16* w2base = w2t + (size_t)(wave*128 + m16)*256 + q*8;
    const u16* hbase  = sh_h + m16*264 + q*8;

    bf16x8 aw[2][8];   // W2t fragments (global, L2-hot), double-buffered
    bf16x8 bh[2][4];   // h fragments (LDS), double-buffered
#pragma unroll
    for (int nt = 0; nt < 8; ++nt)
      aw[0][nt] = *(const bf16x8*)(w2base + nt*4096);
#pragma unroll
    for (int mt = 0; mt < 4; ++mt)
      bh[0][mt] = *(const bf16x8*)(hbase + mt*16*264);

#pragma unroll
    for (int kk = 0; kk < 8; ++kk){
      const int cur = kk & 1, nxt = cur ^ 1;
      if (kk < 7){
#pragma unroll
        for (int nt = 0; nt < 8; ++nt)
          aw[nxt][nt] = *(const bf16x8*)(w2base + nt*4096 + (kk+1)*32);
#pragma unroll
        for (int mt = 0; mt < 4; ++mt)
          bh[nxt][mt] = *(const bf16x8*)(hbase + mt*16*264 + (kk+1)*32);
      }
#pragma unroll
      for (int nt = 0; nt < 8; ++nt)
#pragma unroll
        for (int mt = 0; mt < 4; ++mt)
          acc[nt][mt] = __builtin_amdgcn_mfma_f32_16x16x32_bf16(
              aw[cur][nt], bh[cur][mt], acc[nt][mt], 0, 0, 0);
    }

    // Epilogue: n = wave*128 + nt*16 + q*4 + reg; b = (q&1)*4 + reg;
    // c = wave*16 + nt*2 + (q>>1). Reduce q0+q1 (c even) / q2+q3 (c odd).
#pragma unroll
    for (int mt = 0; mt < 4; ++mt){
      const int mg  = blk*64 + mt*16 + m16;
      const int mgc = (mg < n_pairs) ? mg : (n_pairs - 1);
      f32x4 bb = *(const f32x4*)(basis + (size_t)mgc*8 + (q & 1)*4);
#pragma unroll
      for (int nt = 0; nt < 8; ++nt){
        f32x4 a = acc[nt][mt];
        float s = a[0]*bb[0] + a[1]*bb[1] + a[2]*bb[2] + a[3]*bb[3];
        s += __shfl_xor(s, 16);          // q0+=q1 (c even), q2+=q3 (c odd)
        float v2 = __shfl_xor(s, 32);    // q0 <- the c-odd value
        if (q == 0 && mg < n_pairs){
          f32x2 pk = {s, v2};
          *(f32x2*)(out + (size_t)mg*64 + wave*16 + nt*2) = pk;
        }
      }
    }
  }
}

extern "C" void kernel_launch(void* const* d_in, const int* in_sizes, int n_in,
                              void* d_out, int out_size, void* d_ws, size_t ws_size,
                              hipStream_t stream)
{
  const float* p1    = (const float*)d_in[0];
  const int*   pi    = (const int*)d_in[1];
  const int*   pj    = (const int*)d_in[2];
  const float* basis = (const float*)d_in[3];
  const float* W1    = (const float*)d_in[4];  // [64][256] f32
  const float* W2    = (const float*)d_in[5];  // [256][512] f32
  float* out = (float*)d_out;

  u16* w1t = (u16*)d_ws;                   // [256][64]  bf16 = 32 KB
  u16* w2t = w1t + 64 * 256;               // [512][256] bf16 = 256 KB

  const int n_pairs = in_sizes[1];

  transpose_cast_k<<<dim3(4, 1), 256, 0, stream>>>(W1, w1t, 64, 256);
  transpose_cast_k<<<dim3(8, 4), 256, 0, stream>>>(W2, w2t, 256, 512);

  const int blocks = (n_pairs + 63) / 64;
  pilayer_kernel<<<blocks, 256, 0, stream>>>(p1, pi, pj, basis, w1t, w2t, out, n_pairs);
}

// Round 3
// 615.805 us; speedup vs baseline: 1.1981x; 1.1981x over previous
//
#include <hip/hip_runtime.h>

typedef unsigned short u16;
typedef unsigned int   u32;
typedef __bf16 bf16x8 __attribute__((ext_vector_type(8)));
typedef float  f32x4  __attribute__((ext_vector_type(4)));
typedef float  f32x2  __attribute__((ext_vector_type(2)));
typedef unsigned short u16x8 __attribute__((ext_vector_type(8)));

#define PPB 160   // pairs per block (10 m-tiles)

__device__ __forceinline__ u16 f2bf(float f){
  union { float f; u32 i; } v; v.f = f;
  u32 u = v.i;
  u += 0x7fffu + ((u >> 16) & 1u);   // RNE (finite values only)
  return (u16)(u >> 16);
}
__device__ __forceinline__ float tanh_fast(float x){
  x = fminf(fmaxf(x, -12.f), 12.f);
  float t = __builtin_amdgcn_exp2f(x * 2.885390081777926815f); // e^{2x}
  return (t - 1.f) * __builtin_amdgcn_rcpf(t + 1.f);
}

// ------- transpose+downcast: in f32[R][C] -> out bf16[C][R]; R,C mult of 64
__global__ __launch_bounds__(256) void transpose_cast_k(
    const float* __restrict__ in, u16* __restrict__ out, int R, int C)
{
  __shared__ u16 tile[64][65];
  const int tx = threadIdx.x & 63;
  const int ty = threadIdx.x >> 6;        // 0..3
  const int c0 = blockIdx.x * 64;
  const int r0 = blockIdx.y * 64;
#pragma unroll
  for (int rr = 0; rr < 16; ++rr){
    int r = ty + rr * 4;
    tile[r][tx] = f2bf(in[(size_t)(r0 + r) * C + c0 + tx]);
  }
  __syncthreads();
#pragma unroll
  for (int rr = 0; rr < 16; ++rr){
    int r = ty + rr * 4;
    out[(size_t)(c0 + r) * R + r0 + tx] = tile[tx][r];
  }
}

// ------- W2 f32[256][512] -> w2b bf16[8][512][32]: w2b[kk][n][kl] = W2[kk*32+kl][n]
__global__ __launch_bounds__(256) void w2_block_k(
    const float* __restrict__ in, u16* __restrict__ out)
{
  __shared__ float tile[32][65];
  const int kk = blockIdx.x;       // 0..7
  const int n0 = blockIdx.y * 64;  // 0..448
  const int t  = threadIdx.x;
  {
    int r  = t >> 3;               // k-row 0..31
    int c8 = t & 7;                // 8-col group
    const float* src = in + (size_t)(kk*32 + r)*512 + n0 + c8*8;
    f32x4 v0 = *(const f32x4*)src;
    f32x4 v1 = *(const f32x4*)(src + 4);
#pragma unroll
    for (int e = 0; e < 4; ++e){
      tile[r][c8*8 + e]     = v0[e];
      tile[r][c8*8 + 4 + e] = v1[e];
    }
  }
  __syncthreads();
  {
    int c = t >> 2, part = t & 3;  // c: n within tile, part: 8-k group
    u16x8 o;
#pragma unroll
    for (int e = 0; e < 8; ++e) o[e] = f2bf(tile[part*8 + e][c]);
    *(u16x8*)(out + ((size_t)kk*512 + n0 + c)*32 + part*8) = o;
  }
}

// ---------------- fused PILayer kernel, 160 pairs / 512 threads ----------------
// Wave w owns W2 rows n in [w*64, w*64+64) -> persistent regs awf[8][4] (128 VGPR)
// Phase 0: inter = bf16(p1[i]+p1[j]) -> sh_inter[160][72]
// Phase 1: h = bf16(tanh(inter @ W1)) -> sh_h[160][264]
// Phase 2: per m-tile: h2 = h @ W2 (fp32 acc, D[n][m]), fold basis, store out
__global__ __launch_bounds__(512, 2) void pilayer_kernel(
    const float* __restrict__ p1,     // [N_NODES][64] f32
    const int* __restrict__ pair_i,   // [NP]
    const int* __restrict__ pair_j,   // [NP]
    const float* __restrict__ basis,  // [NP][8] f32
    const u16* __restrict__ w1t,      // [256][64] bf16
    const u16* __restrict__ w2b,      // [8][512][32] bf16 (k-blocked W2^T)
    float* __restrict__ out,          // [NP][64] f32
    int n_pairs)
{
  extern __shared__ __align__(16) u16 smem[];
  u16* sh_h     = smem;              // [160][264] = 84480 B
  u16* sh_inter = smem + PPB * 264;  // [160][72]  = 23040 B

  const int tid  = threadIdx.x;
  const int blk  = blockIdx.x;
  const int lane = tid & 63;
  const int w    = tid >> 6;     // wave 0..7
  const int m16  = lane & 15;
  const int q    = lane >> 4;    // quad 0..3

  // ---- Persistent W2 fragment load (issued first, drains under phases 0/1) ----
  bf16x8 awf[8][4];
#pragma unroll
  for (int kk = 0; kk < 8; ++kk)
#pragma unroll
    for (int nt = 0; nt < 4; ++nt)
      awf[kk][nt] = *(const bf16x8*)(
          w2b + ((size_t)kk*512 + w*64 + nt*16 + m16)*32 + q*8);
  __builtin_amdgcn_sched_barrier(0);   // keep these loads issued up-front

  // ---- Phase 0: gather inter = bf16(p1[i] + p1[j]) into LDS ----
  for (int u = tid; u < PPB * 4; u += 512){
    int m   = u >> 2;            // pair row 0..159
    int seg = u & 3;             // 16 floats per segment
    int p   = blk * PPB + m;
    if (p >= n_pairs) p = n_pairs - 1;
    const f32x4* pi = (const f32x4*)(p1 + (size_t)pair_i[p] * 64 + seg * 16);
    const f32x4* pj = (const f32x4*)(p1 + (size_t)pair_j[p] * 64 + seg * 16);
    f32x4 a0 = pi[0], a1 = pi[1], a2 = pi[2], a3 = pi[3];
    f32x4 b0 = pj[0], b1 = pj[1], b2 = pj[2], b3 = pj[3];
    u16x8 r0, r1;
#pragma unroll
    for (int e = 0; e < 4; ++e){
      r0[e]     = f2bf(a0[e] + b0[e]);
      r0[e + 4] = f2bf(a1[e] + b1[e]);
      r1[e]     = f2bf(a2[e] + b2[e]);
      r1[e + 4] = f2bf(a3[e] + b3[e]);
    }
    u16x8* dst = (u16x8*)(sh_inter + m * 72 + seg * 16);
    dst[0] = r0; dst[1] = r1;
  }
  __syncthreads();

  // ---- Phase 1: h = bf16(tanh(inter @ W1)) -> sh_h ----
  // Wave w computes n-rows [w*32, w*32+32) for all 160 pairs.
  {
    bf16x8 af[2][2];
#pragma unroll
    for (int nt1 = 0; nt1 < 2; ++nt1)
#pragma unroll
      for (int kh = 0; kh < 2; ++kh)
        af[nt1][kh] = *(const bf16x8*)(
            w1t + (size_t)(w*32 + nt1*16 + m16)*64 + kh*32 + q*8);

    for (int mt1 = 0; mt1 < PPB/16; ++mt1){
      const u16* irow = sh_inter + (mt1*16 + m16)*72 + q*8;
      bf16x8 b0 = *(const bf16x8*)(irow);
      bf16x8 b1 = *(const bf16x8*)(irow + 32);
#pragma unroll
      for (int nt1 = 0; nt1 < 2; ++nt1){
        f32x4 acc = {0.f, 0.f, 0.f, 0.f};
        acc = __builtin_amdgcn_mfma_f32_16x16x32_bf16(af[nt1][0], b0, acc, 0, 0, 0);
        acc = __builtin_amdgcn_mfma_f32_16x16x32_bf16(af[nt1][1], b1, acc, 0, 0, 0);
        u32 lo = (u32)f2bf(tanh_fast(acc[0])) | ((u32)f2bf(tanh_fast(acc[1])) << 16);
        u32 hi = (u32)f2bf(tanh_fast(acc[2])) | ((u32)f2bf(tanh_fast(acc[3])) << 16);
        u32* dst = (u32*)(sh_h + (size_t)(mt1*16 + m16)*264 + w*32 + nt1*16 + q*4);
        dst[0] = lo; dst[1] = hi;
      }
    }
  }
  __syncthreads();

  // ---- Phase 2: per m-tile GEMM2 against register-resident W2, fold basis ----
  for (int mt = 0; mt < PPB/16; ++mt){
    const int mg  = blk * PPB + mt*16 + m16;
    const int mgc = (mg < n_pairs) ? mg : (n_pairs - 1);
    f32x4 bb = *(const f32x4*)(basis + (size_t)mgc*8 + (q & 1)*4);

    const u16* hrow = sh_h + (size_t)(mt*16 + m16)*264 + q*8;
    f32x4 acc[4];
#pragma unroll
    for (int nt = 0; nt < 4; ++nt) acc[nt] = (f32x4){0.f, 0.f, 0.f, 0.f};

    bf16x8 bh = *(const bf16x8*)(hrow);
#pragma unroll
    for (int kk = 0; kk < 8; ++kk){
      bf16x8 bhn;
      if (kk < 7) bhn = *(const bf16x8*)(hrow + (kk + 1)*32);
#pragma unroll
      for (int nt = 0; nt < 4; ++nt)
        acc[nt] = __builtin_amdgcn_mfma_f32_16x16x32_bf16(
            awf[kk][nt], bh, acc[nt], 0, 0, 0);
      bh = bhn;
    }

    // n = w*64 + nt*16 + q*4 + reg; c = w*8 + nt*2 + (q>>1); b = (q&1)*4 + reg
#pragma unroll
    for (int nt = 0; nt < 4; ++nt){
      f32x4 a = acc[nt];
      float s = a[0]*bb[0] + a[1]*bb[1] + a[2]*bb[2] + a[3]*bb[3];
      s += __shfl_xor(s, 16);          // sum b-halves (q0+q1 / q2+q3)
      float v2 = __shfl_xor(s, 32);    // partner c-channel
      if (q == 0 && mg < n_pairs){
        f32x2 pk = {s, v2};
        *(f32x2*)(out + (size_t)mg*64 + w*8 + nt*2) = pk;
      }
    }
  }
}

extern "C" void kernel_launch(void* const* d_in, const int* in_sizes, int n_in,
                              void* d_out, int out_size, void* d_ws, size_t ws_size,
                              hipStream_t stream)
{
  const float* p1    = (const float*)d_in[0];
  const int*   pi    = (const int*)d_in[1];
  const int*   pj    = (const int*)d_in[2];
  const float* basis = (const float*)d_in[3];
  const float* W1    = (const float*)d_in[4];  // [64][256] f32
  const float* W2    = (const float*)d_in[5];  // [256][512] f32
  float* out = (float*)d_out;

  u16* w1t = (u16*)d_ws;                   // [256][64]   bf16 = 32 KB
  u16* w2b = w1t + 64 * 256;               // [8][512][32] bf16 = 256 KB

  const int n_pairs = in_sizes[1];
  const int lds_bytes = (PPB * 264 + PPB * 72) * (int)sizeof(u16);  // 107520

  static int attr_done = 0;  // attribute is device-global state, not stream work;
  if (!attr_done){           // first (uncaptured) call sets it before capture
    hipFuncSetAttribute((const void*)pilayer_kernel,
                        hipFuncAttributeMaxDynamicSharedMemorySize, lds_bytes);
    attr_done = 1;
  }

  transpose_cast_k<<<dim3(4, 1), 256, 0, stream>>>(W1, w1t, 64, 256);
  w2_block_k<<<dim3(8, 8), 256, 0, stream>>>(W2, w2b);

  const int blocks = (n_pairs + PPB - 1) / PPB;
  pilayer_kernel<<<blocks, 512, lds_bytes, stream>>>(
      p1, pi, pj, basis, w1t, w2b, out, n_pairs);
}